// Round 16
// baseline (632.295 us; speedup 1.0000x reference)
//
#include <hip/hip_runtime.h>
#include <hip/hip_bf16.h>

typedef __hip_bfloat16 bf16;
typedef __attribute__((ext_vector_type(8))) short short8_t;
typedef __attribute__((ext_vector_type(4))) unsigned short ushort4_t;
typedef __attribute__((ext_vector_type(4))) float float4_t;
typedef __attribute__((ext_vector_type(16))) float float16_t;

#define NN 5000
#define EE 8192
#define DM 200
#define NLAY 6
#define NFC 96
#define PPOS 196
#define FLATK 18816
#define NCLS 13
#define EPSC 1e-5f
// fcr coalesced layout: [dgrp(7)][pt(7)][g(6)][kch(64)][row(32)][8 bf16]
#define FCRN (7*7*6*64*32*8)   // 4,816,896 elements = 9.6 MB

__device__ __forceinline__ float b2f(bf16 v){ return __bfloat162float(v); }
__device__ __forceinline__ float us2f(unsigned short u){ return __uint_as_float(((unsigned int)u) << 16); }
__device__ __forceinline__ float ldf(const void* p, int i, int bf){
  return bf ? b2f(((const bf16*)p)[i]) : ((const float*)p)[i];
}
__device__ __forceinline__ unsigned short f2bu(float f){
  bf16 b = __float2bfloat16(f);
  unsigned short u;
  __builtin_memcpy(&u, &b, 2);
  return u;
}
__device__ __forceinline__ int clampN(int g){ return ((unsigned)g < (unsigned)NN) ? g : 0; }

// ---------------- dtype probe ----------------
__global__ void k_dtype(const void* __restrict__ bn1g, int* __restrict__ flag){
  if (blockIdx.x == 0 && threadIdx.x == 0)
    *flag = (*(const unsigned short*)bn1g == 0x3F80u) ? 1 : 0;
}

// ---------------- inputs -> working copies: x fp32, r/ir bf16 (quad-vectorized) ----
__global__ void k_cvt(const void* __restrict__ nfeat, const void* __restrict__ ef,
                      const void* __restrict__ ief, float* __restrict__ x0,
                      bf16* __restrict__ r0, bf16* __restrict__ ir0,
                      const int* __restrict__ dtf){
  const int bf = *dtf;
  const int totq = (NN*DM + 2*EE*DM) / 4;
  for (int q = blockIdx.x*blockDim.x + threadIdx.x; q < totq; q += gridDim.x*blockDim.x){
    int i = q*4;
    if (i < NN*DM){
      if (bf){
        ushort4_t v = *(const ushort4_t*)((const unsigned short*)nfeat + i);
        float4 o; o.x = us2f(v[0]); o.y = us2f(v[1]); o.z = us2f(v[2]); o.w = us2f(v[3]);
        *(float4*)(x0 + i) = o;
      } else {
        *(float4*)(x0 + i) = *(const float4*)((const float*)nfeat + i);
      }
    } else if (i < NN*DM + EE*DM){
      int j = i - NN*DM;
      if (bf){
        *(ushort4_t*)((unsigned short*)r0 + j) = *(const ushort4_t*)((const unsigned short*)ef + j);
      } else {
        float4 v = *(const float4*)((const float*)ef + j);
        ushort4_t o; o[0] = f2bu(v.x); o[1] = f2bu(v.y); o[2] = f2bu(v.z); o[3] = f2bu(v.w);
        *(ushort4_t*)((unsigned short*)r0 + j) = o;
      }
    } else {
      int j = i - NN*DM - EE*DM;
      if (bf){
        *(ushort4_t*)((unsigned short*)ir0 + j) = *(const ushort4_t*)((const unsigned short*)ief + j);
      } else {
        float4 v = *(const float4*)((const float*)ief + j);
        ushort4_t o; o[0] = f2bu(v.x); o[1] = f2bu(v.y); o[2] = f2bu(v.z); o[3] = f2bu(v.w);
        *(ushort4_t*)((unsigned short*)ir0 + j) = o;
      }
    }
  }
}

__global__ void k_zero(float* __restrict__ p, int n){
  int i = blockIdx.x*blockDim.x + threadIdx.x;
  if (i < n) p[i] = 0.f;
}

__global__ void k_deg(const int* __restrict__ ei0, const int* __restrict__ iei0,
                      float* __restrict__ degf, float* __restrict__ degi){
  int e = blockIdx.x*blockDim.x + threadIdx.x;
  if (e < EE){
    atomicAdd(&degf[clampN(ei0[e])], 1.f);
    atomicAdd(&degi[clampN(iei0[e])], 1.f);
  }
}

// dinv folded in: f(d) = d>0 ? rsqrt(d) : 0   (degrees are integers >= 0)
__global__ void k_norm(const int* __restrict__ ei, const int* __restrict__ iei,
                       const float* __restrict__ degf, const float* __restrict__ degi,
                       float* __restrict__ nfv, float* __restrict__ niv){
  int e = blockIdx.x*blockDim.x + threadIdx.x;
  if (e < EE){
    float ds0 = degf[clampN(ei[e])];
    float ds1 = degf[clampN(ei[EE + e])];
    float di0 = degi[clampN(iei[e])];
    float di1 = degi[clampN(iei[EE + e])];
    float f0 = ds0 > 0.f ? rsqrtf(ds0) : 0.f;
    float f1 = ds1 > 0.f ? rsqrtf(ds1) : 0.f;
    float g0 = di0 > 0.f ? rsqrtf(di0) : 0.f;
    float g1 = di1 > 0.f ? rsqrtf(di1) : 0.f;
    nfv[e] = f0 * f1;
    niv[e] = g0 * g1;
  }
}

// ---------------- fc_w repack, v8 coalesced layout ----------------
__global__ void k_fcr(const void* __restrict__ fc_w, bf16* __restrict__ outp,
                      const int* __restrict__ dtf){
  const int bf = *dtf;
  int i = blockIdx.x*blockDim.x + threadIdx.x;
  if (i >= FCRN) return;
  int j    = i & 7;
  int row  = (i >> 3) & 31;
  int kch  = (i >> 8) & 63;
  int rest = i >> 14;            // (dgrp*7 + pt)*6 + g
  int g = rest % 6;
  int rest2 = rest / 6;          // dgrp*7 + pt
  int pt = rest2 % 7;
  int dgrp = rest2 / 7;
  int d = dgrp*32 + row;
  int cl = kch >> 2, pidx = kch & 3;
  int p = pt*32 + pidx*8 + j;
  int c = g*16 + cl;
  float v = 0.f;
  if (p < PPOS && d < DM) v = ldf(fc_w, d*FLATK + c*PPOS + p, bf);
  outp[i] = __float2bfloat16(v);
}

// ---------------- weight transpose: wt[job][layer][n<224][k<208] bf16 ----------------
__global__ void k_wt(const void* __restrict__ Winp, const void* __restrict__ Woutp,
                     const void* __restrict__ Wloopp, const void* __restrict__ Wrelp,
                     bf16* __restrict__ wt, const int* __restrict__ dtf){
  const int bf = *dtf;
  const int per = 6*224*208;
  int i = blockIdx.x*blockDim.x + threadIdx.x;
  if (i >= 4*per) return;
  int job = i / per, rem = i - job*per;
  int layer = rem / (224*208), rem2 = rem - layer*(224*208);
  int n = rem2 / 208, k = rem2 - n*208;
  const void* src = (job==0) ? Wloopp : (job==1) ? Winp : (job==2) ? Woutp : Wrelp;
  float v = 0.f;
  if (n < DM && k < DM) v = ldf(src, (layer*DM + k)*DM + n, bf);
  wt[i] = __float2bfloat16(v);
}

// ---------------- GCN layer: both phases, ONE dispatch; v18 MLP-batched staging -----
// 1181 blocks: 157 job0 (x@Wloop, non-atomic into xw) + 256 job1 + 256 job2
//            + 256 job3 (r@Wrel) + 256 job4.
// v18: staging split into load-batch (7 statically-indexed quad slots, all loads
// issued back-to-back -> 7 outstanding gathers/thread) then convert+LDS-store.
// Guarded loads; zero-init slots flow zeros through all job formulas.
// NOTE: plain __launch_bounds__ — explicit occupancy attributes collapse the
// allocator to the 64-reg tier and spill (measured v4/v12/v14: 180 MB scratch).
__global__ __launch_bounds__(256) void k_gcn(
    const float* __restrict__ x,
    const bf16* __restrict__ rin, const bf16* __restrict__ irin,
    bf16* __restrict__ rout, bf16* __restrict__ irout,
    const int* __restrict__ ei, const int* __restrict__ iei,
    const float* __restrict__ nfv, const float* __restrict__ niv,
    const bf16* __restrict__ wt, int layer, float* __restrict__ agg,
    float* __restrict__ xw)
{
  __shared__ short Ah[32][216];
  __shared__ short Al[32][216];
  __shared__ int dst_s[32];
  const int tid = threadIdx.x;
  const int bid = blockIdx.x;
  int job, m0;
  if (bid < 157){ job = 0; m0 = bid*32; }
  else if (bid < 413){ job = 1; m0 = (bid-157)*32; }
  else if (bid < 669){ job = 2; m0 = (bid-413)*32; }
  else if (bid < 925){ job = 3; m0 = (bid-669)*32; }
  else { job = 4; m0 = (bid-925)*32; }
  const int wsel = (job <= 2) ? job : 3;
  const bf16* W = wt + (wsel*6 + layer)*224*208;
  const bool do_lo = (job <= 2);

  if (tid < 32){
    int row = m0 + tid;
    int d = 0;
    if (job == 1) d = clampN(ei[EE + row]);
    else if (job == 2) d = clampN(iei[EE + row]);
    dst_s[tid] = d;
  }
  // ---- staging phase 1: issue all gathers (7 slots, statically indexed) ----
  {
    float4 xv[7]; ushort4_t rv[7]; float nfa[7];
    #pragma unroll
    for (int it = 0; it < 7; it++){
      float4 z = {0.f,0.f,0.f,0.f}; xv[it] = z;
      ushort4_t uz; uz[0]=0; uz[1]=0; uz[2]=0; uz[3]=0; rv[it] = uz;
      nfa[it] = 0.f;
      int t = tid + it*256;
      if (t < 32*52){
        int m = t / 52, q = t - m*52;
        int k = q*4, row = m0 + m;
        if (q < 50){
          if (job == 0){
            if (row < NN) xv[it] = *(const float4*)(x + row*DM + k);
          } else if (job <= 2){
            const int* idx = (job == 1) ? ei : iei;
            const bf16* rr = (job == 1) ? rin : irin;
            xv[it] = *(const float4*)(x + clampN(idx[row])*DM + k);
            rv[it] = *(const ushort4_t*)((const unsigned short*)rr + row*DM + k);
            nfa[it] = (job == 1) ? nfv[row] : niv[row];
          } else {
            const bf16* rr = (job == 3) ? rin : irin;
            rv[it] = *(const ushort4_t*)((const unsigned short*)rr + row*DM + k);
          }
        }
      }
    }
    // ---- staging phase 2: convert + LDS store ----
    #pragma unroll
    for (int it = 0; it < 7; it++){
      int t = tid + it*256;
      if (t < 32*52){
        int m = t / 52, q = t - m*52;
        int k = q*4;
        float a0, a1, a2, a3;
        if (job == 0){
          a0 = xv[it].x; a1 = xv[it].y; a2 = xv[it].z; a3 = xv[it].w;
        } else if (job <= 2){
          float nf = nfa[it];
          a0 = (xv[it].x - us2f(rv[it][0])) * nf;
          a1 = (xv[it].y - us2f(rv[it][1])) * nf;
          a2 = (xv[it].z - us2f(rv[it][2])) * nf;
          a3 = (xv[it].w - us2f(rv[it][3])) * nf;
        } else {
          a0 = us2f(rv[it][0]); a1 = us2f(rv[it][1]);
          a2 = us2f(rv[it][2]); a3 = us2f(rv[it][3]);
        }
        unsigned short h0 = f2bu(a0), h1 = f2bu(a1), h2 = f2bu(a2), h3 = f2bu(a3);
        ushort4_t hv; hv[0] = h0; hv[1] = h1; hv[2] = h2; hv[3] = h3;
        *(ushort4_t*)&Ah[m][k] = hv;
        if (do_lo){
          ushort4_t lv;
          lv[0] = f2bu(a0 - us2f(h0));
          lv[1] = f2bu(a1 - us2f(h1));
          lv[2] = f2bu(a2 - us2f(h2));
          lv[3] = f2bu(a3 - us2f(h3));
          *(ushort4_t*)&Al[m][k] = lv;
        }
      }
    }
  }
  __syncthreads();

  const int lane = tid & 63, wave = tid >> 6;
  const int half = lane >> 5, ln = lane & 31;
  const bool has2 = (wave < 3);
  const bf16* Wn0 = W + (wave*32 + ln)*208;
  const bf16* Wn1 = W + ((wave+4)*32 + ln)*208;
  float16_t acc0 = {};
  float16_t acc1 = {};
  #pragma unroll
  for (int kk = 0; kk < 13; kk++){
    const int ko = kk*16 + half*8;
    short8_t ahf = *(const short8_t*)&Ah[ln][ko];
    short8_t b0 = *(const short8_t*)(Wn0 + ko);
    acc0 = __builtin_amdgcn_mfma_f32_32x32x16_bf16(ahf, b0, acc0, 0, 0, 0);
    short8_t alf = {};
    if (do_lo){
      alf = *(const short8_t*)&Al[ln][ko];
      acc0 = __builtin_amdgcn_mfma_f32_32x32x16_bf16(alf, b0, acc0, 0, 0, 0);
    }
    if (has2){
      short8_t b1 = *(const short8_t*)(Wn1 + ko);
      acc1 = __builtin_amdgcn_mfma_f32_32x32x16_bf16(ahf, b1, acc1, 0, 0, 0);
      if (do_lo)
        acc1 = __builtin_amdgcn_mfma_f32_32x32x16_bf16(alf, b1, acc1, 0, 0, 0);
    }
  }
  #pragma unroll
  for (int s = 0; s < 2; s++){
    if (s == 1 && !has2) break;
    int n = ((s ? wave+4 : wave)*32) + ln;
    if (n >= DM) continue;
    #pragma unroll
    for (int rr = 0; rr < 16; rr++){
      int m = (rr & 3) + 8*(rr >> 2) + 4*half;
      int row = m0 + m;
      float v = s ? acc1[rr] : acc0[rr];
      if (job == 0){ if (row < NN) xw[row*DM + n] = v; }        // exclusive rows: no atomic
      else if (job <= 2){ atomicAdd(&agg[dst_s[m]*DM + n], v); }
      else if (job == 3){ rout[row*DM + n] = __float2bfloat16(v); }
      else              { irout[row*DM + n] = __float2bfloat16(v); }
    }
  }
}

// tanh epilogue, float4: xw holds job0's partial; agg holds jobs 1/2 scatter sums.
__global__ void k_tanh(float* __restrict__ agg, const void* __restrict__ bgcn,
                       int l, float* __restrict__ xw, const int* __restrict__ dtf){
  const int bf = *dtf;
  int q = blockIdx.x*blockDim.x + threadIdx.x;
  if (q < NN*DM/4){
    int idx = q*4;
    int d = idx % DM;           // DM%4==0 -> d..d+3 within row
    float4 a = *(const float4*)(agg + idx);
    float4 xv = *(const float4*)(xw + idx);
    xv.x = tanhf((a.x + xv.x)*(1.f/3.f) + ldf(bgcn, l*DM + d, bf));
    xv.y = tanhf((a.y + xv.y)*(1.f/3.f) + ldf(bgcn, l*DM + d + 1, bf));
    xv.z = tanhf((a.z + xv.z)*(1.f/3.f) + ldf(bgcn, l*DM + d + 2, bf));
    xv.w = tanhf((a.w + xv.w)*(1.f/3.f) + ldf(bgcn, l*DM + d + 3, bf));
    *(float4*)(xw + idx) = xv;
    float4 z = {0.f, 0.f, 0.f, 0.f};
    *(float4*)(agg + idx) = z;
  }
}

// ---------------- fused ConvE decoder (champion: coalesced fcr + fc1 fused) ----------------
// UNCHANGED from the 587us champion.
__global__ __launch_bounds__(512) void k_conve(
    const float* __restrict__ xf, const bf16* __restrict__ rf,
    const int* __restrict__ ei0,
    const void* __restrict__ bn0g, const void* __restrict__ bn0b,
    const void* __restrict__ conv_w, const void* __restrict__ conv_b,
    const void* __restrict__ bn1g, const void* __restrict__ bn1b,
    const bf16* __restrict__ fcr, const void* __restrict__ fc_b,
    const void* __restrict__ bn2g, const void* __restrict__ bn2b,
    const void* __restrict__ fc1w, const void* __restrict__ fc1b,
    void* __restrict__ outp, const int* __restrict__ dtf)
{
  const int bfm = *dtf;
  __shared__ __attribute__((aligned(16))) unsigned short img_s[32][400];  // 25.6 KB
  __shared__ __attribute__((aligned(16))) short P_s[3*32*520];            // 99.8 KB
  __shared__ __attribute__((aligned(16))) unsigned short cw_s[96*72];     // 13.8 KB
  __shared__ float bnp_s[3][96];                                          // 1.2 KB
  const int tid = threadIdx.x;
  const int e0 = blockIdx.x * 32;
  const int lane = tid & 63;
  const int wave = tid >> 6;
  const int half = lane >> 5;
  const int ln   = lane & 31;
  const int m16  = lane & 15;
  const int q4   = (lane >> 4) & 3;

  {
    const float s0 = ldf(bn0g, 0, bfm) * rsqrtf(1.f + EPSC);
    const float c0 = ldf(bn0b, 0, bfm);
    for (int t = tid; t < 32*400; t += 512){
      int me = t / 400, i = t - me*400;
      int e = e0 + me;
      int j = i >> 1;
      float v = (i & 1) ? b2f(rf[e*DM + j]) : xf[clampN(ei0[e])*DM + j];
      img_s[me][i] = f2bu(v * s0 + c0);
    }
    for (int t = tid; t < 96*72; t += 512){
      int c = t / 72, tau = t - c*72;
      float v = (tau < 49) ? ldf(conv_w, c*49 + tau, bfm) : 0.f;
      cw_s[t] = f2bu(v);
    }
    if (tid < 96){
      bnp_s[0][tid] = ldf(bn1g, tid, bfm) * rsqrtf(1.f + EPSC);
      bnp_s[1][tid] = ldf(bn1b, tid, bfm);
      bnp_s[2][tid] = ldf(conv_b, tid, bfm);
    }
  }

  int doff[2][8];
  #pragma unroll
  for (int kk = 0; kk < 2; kk++)
    #pragma unroll
    for (int j = 0; j < 8; j++){
      int tau = kk*32 + q4*8 + j;
      int kh = tau / 7, kw = tau - kh*7;
      doff[kk][j] = (tau < 49) ? kh*20 + kw : 0;
    }

  const int dA0 = wave*32 + ln;
  const bool fcact = (wave < 7);
  float16_t facc = {};

  __syncthreads();

#define FLOAD(BUF, BIDX) { \
    _Pragma("unroll") \
    for (int t_ = 0; t_ < 8; t_++){ \
      int it_ = (BIDX)*8 + t_; \
      int g_ = it_ >> 5; int itm_ = it_ & 31; int kch_ = itm_*2 + half; \
      BUF[t_] = *(const short8_t*)(frW + (g_*64 + kch_)*256 + ln*8); \
    } }
#define FCONS(BUF, BIDX) { \
    _Pragma("unroll") \
    for (int t_ = 0; t_ < 8; t_++){ \
      int it_ = (BIDX)*8 + t_; \
      int g_ = it_ >> 5; int itm_ = it_ & 31; int kch_ = itm_*2 + half; \
      int cl_ = kch_ >> 2, pidx_ = kch_ & 3; \
      short8_t af_ = *(const short8_t*)&P_s[g_*16640 + ln*520 + cl_*32 + ((pidx_ ^ (cl_ & 3))*8)]; \
      facc = __builtin_amdgcn_mfma_f32_32x32x16_bf16(af_, BUF[t_], facc, 0, 0, 0); \
    } }
#define PSTORE(CA, MS) { \
    _Pragma("unroll") \
    for (int r2_ = 0; r2_ < 2; r2_++){ \
      int ploc_ = (MS)*16 + q4*4 + r2_*2; \
      int pg_ = pt*32 + ploc_; \
      float v0_ = ((CA)[r2_*2]   + cbv) * s1v + bb1v;  v0_ = v0_ > 0.f ? v0_ : 0.f; \
      float v1_ = ((CA)[r2_*2+1] + cbv) * s1v + bb1v;  v1_ = v1_ > 0.f ? v1_ : 0.f; \
      if (pg_     >= PPOS) v0_ = 0.f; \
      if (pg_ + 1 >= PPOS) v1_ = 0.f; \
      unsigned int pk_ = (unsigned int)f2bu(v0_) | ((unsigned int)f2bu(v1_) << 16); \
      int sb_ = (ploc_ >> 3) ^ (m16 & 3); \
      *(unsigned int*)&P_s[g*16640 + eL*520 + m16*32 + sb_*8 + (ploc_ & 7)] = pk_; \
    } }

  #pragma unroll 1
  for (int pt = 0; pt < 7; pt++){
    int pbase0, pbase1;
    {
      int p0 = pt*32 + m16;
      int p1 = pt*32 + 16 + m16;
      int oh0 = p0 / 14, ow0 = p0 - oh0*14;
      int oh1 = p1 / 14, ow1 = p1 - oh1*14;
      pbase0 = (p0 < PPOS) ? oh0*20 + ow0 : 0;
      pbase1 = (p1 < PPOS) ? oh1*20 + ow1 : 0;
    }
    #pragma unroll 1
    for (int sub = 0; sub < 2; sub++){
      const bf16* frW = fcr + ((wave*7 + pt)*6 + sub*3)*16384;
      short8_t BbA[8], BbB[8];
      if (fcact) FLOAD(BbA, 0);

      #pragma unroll
      for (int e = 0; e < 4; e++){
        const int eL = wave*4 + e;
        const unsigned short* ib = &img_s[eL][0];
        short8_t A00, A01, A10, A11;
        #pragma unroll
        for (int j = 0; j < 8; j++){
          A00[j] = (short)ib[pbase0 + doff[0][j]];
          A01[j] = (short)ib[pbase0 + doff[1][j]];
          A10[j] = (short)ib[pbase1 + doff[0][j]];
          A11[j] = (short)ib[pbase1 + doff[1][j]];
        }
        #pragma unroll
        for (int g = 0; g < 3; g++){
          const int cidx = (sub*3 + g)*16 + m16;
          short8_t Bg0 = *(const short8_t*)&cw_s[cidx*72 + q4*8];
          short8_t Bg1 = *(const short8_t*)&cw_s[cidx*72 + 32 + q4*8];
          const float s1v  = bnp_s[0][cidx];
          const float bb1v = bnp_s[1][cidx];
          const float cbv  = bnp_s[2][cidx];
          float4_t ca0 = {0.f,0.f,0.f,0.f};
          ca0 = __builtin_amdgcn_mfma_f32_16x16x32_bf16(A00, Bg0, ca0, 0, 0, 0);
          ca0 = __builtin_amdgcn_mfma_f32_16x16x32_bf16(A01, Bg1, ca0, 0, 0, 0);
          PSTORE(ca0, 0);
          float4_t ca1 = {0.f,0.f,0.f,0.f};
          ca1 = __builtin_amdgcn_mfma_f32_16x16x32_bf16(A10, Bg0, ca1, 0, 0, 0);
          ca1 = __builtin_amdgcn_mfma_f32_16x16x32_bf16(A11, Bg1, ca1, 0, 0, 0);
          PSTORE(ca1, 1);
        }
      }
      __syncthreads();
      if (fcact){
        #pragma unroll 1
        for (int bb = 0; bb < 6; bb++){
          const int b0 = bb*2, b1 = bb*2 + 1;
          FLOAD(BbB, b1);
          FCONS(BbA, b0);
          if (bb < 5) FLOAD(BbA, b0 + 2);
          FCONS(BbB, b1);
        }
      }
      __syncthreads();
    }
  }

  // ---- epilogue 1: h2 = relu((facc + fc_b)*s2 + bn2b) -> LDS (P_s reused) ----
  float* h2s = (float*)P_s;    // 32 x 204 f32 (float4-aligned rows)
  if (fcact && dA0 < DM){
    const float s2  = ldf(bn2g, dA0, bfm) * rsqrtf(1.f + EPSC);
    const float bb2 = ldf(bn2b, dA0, bfm);
    const float fb  = ldf(fc_b, dA0, bfm);
    #pragma unroll
    for (int rr = 0; rr < 16; rr++){
      int m = (rr & 3) + 8*(rr >> 2) + 4*half;
      float v = (facc[rr] + fb) * s2 + bb2;
      h2s[m*204 + dA0] = v > 0.f ? v : 0.f;
    }
  }
  __syncthreads();
  // ---- epilogue 2: fused fc1 -> d_out (32 edges x 13 classes), float4 LDS reads ----
  if (tid < 32*NCLS){
    int e = tid / NCLS, n = tid - e*NCLS;
    const float4* h4p = (const float4*)(h2s + e*204);
    float s = ldf(fc1b, n, bfm);
    #pragma unroll 2
    for (int d4 = 0; d4 < 50; d4++){
      float4 h4 = h4p[d4];
      int d = d4*4;
      s += h4.x * ldf(fc1w, n*DM + d, bfm);
      s += h4.y * ldf(fc1w, n*DM + d + 1, bfm);
      s += h4.z * ldf(fc1w, n*DM + d + 2, bfm);
      s += h4.w * ldf(fc1w, n*DM + d + 3, bfm);
    }
    int idx = (e0 + e)*NCLS + n;
    if (bfm) ((bf16*)outp)[idx] = __float2bfloat16(s);
    else     ((float*)outp)[idx] = s;
  }
#undef FLOAD
#undef FCONS
#undef PSTORE
}

extern "C" void kernel_launch(void* const* d_in, const int* in_sizes, int n_in,
                              void* d_out, int out_size, void* d_ws, size_t ws_size,
                              hipStream_t stream){
  const void* nfeat = d_in[0];
  const void* ef    = d_in[1];
  const void* ief   = d_in[2];
  const void* Winp  = d_in[3];
  const void* Woutp = d_in[4];
  const void* Wloopp= d_in[5];
  const void* Wrelp = d_in[6];
  const void* bgcn  = d_in[7];
  const void* bn0g  = d_in[8];
  const void* bn0b  = d_in[9];
  const void* convw = d_in[10];
  const void* convb = d_in[11];
  const void* bn1g  = d_in[12];
  const void* bn1b  = d_in[13];
  const void* fcw   = d_in[14];
  const void* fcb   = d_in[15];
  const void* bn2g  = d_in[16];
  const void* bn2b  = d_in[17];
  const void* fc1w  = d_in[18];
  const void* fc1b  = d_in[19];
  const int* ei     = (const int*)d_in[20];   // [2][EE]
  const int* iei    = (const int*)d_in[21];

  // ---- workspace carve: ~30.5 MB ----
  char* base = (char*)d_ws;
  int*   dtf  = (int*)base;                      base += 16;
  float* x0   = (float*)base;                    base += NN*DM*4;
  float* x1   = (float*)base;                    base += NN*DM*4;
  float* agg  = (float*)base;                    base += NN*DM*4;
  float* degf = (float*)base;                    base += NN*4;
  float* degi = (float*)base;                    base += NN*4;
  float* nfv  = (float*)base;                    base += EE*4;
  float* niv  = (float*)base;                    base += EE*4;
  bf16*  r0   = (bf16*)base;                     base += EE*DM*2;
  bf16*  ir0  = (bf16*)base;                     base += EE*DM*2;
  bf16*  wt   = (bf16*)base;                     base += 4*6*224*208*2;
  bf16*  fcr  = (bf16*)base;                     base += FCRN*2;   // 9.6 MB
  // r/ir double-buffer scratch lives in the fcr region during the GCN loop
  // (fcr packed AFTER the loop; 6 layers = even #swaps -> final r/ir back in r0/ir0)
  bf16*  rB   = fcr;
  bf16*  irB  = fcr + EE*DM;

  const dim3 B(256);
  k_dtype<<<dim3(1), dim3(64), 0, stream>>>(bn1g, dtf);
  k_cvt<<<dim3(1024), B, 0, stream>>>(nfeat, ef, ief, x0, r0, ir0, dtf);
  k_zero<<<dim3((2*NN + 255)/256), B, 0, stream>>>(degf, 2*NN);
  k_zero<<<dim3((NN*DM + 255)/256), B, 0, stream>>>(agg, NN*DM);
  k_deg<<<dim3((EE + 255)/256), B, 0, stream>>>(ei, iei, degf, degi);
  k_norm<<<dim3((EE + 255)/256), B, 0, stream>>>(ei, iei, degf, degi, nfv, niv);
  k_wt<<<dim3((4*6*224*208 + 255)/256), B, 0, stream>>>(Winp, Woutp, Wloopp, Wrelp, wt, dtf);

  float* xc = x0; float* xn = x1;
  bf16* rc = r0;  bf16* irc = ir0;
  bf16* rn = rB;  bf16* irn = irB;
  for (int l = 0; l < NLAY; l++){
    k_gcn<<<dim3(1181), B, 0, stream>>>(xc, rc, irc, rn, irn, ei, iei, nfv, niv, wt, l, agg, xn);
    k_tanh<<<dim3((NN*DM/4 + 255)/256), B, 0, stream>>>(agg, bgcn, l, xn, dtf);
    float* t = xc; xc = xn; xn = t;
    bf16* tr = rc; rc = rn; rn = tr;
    bf16* ti = irc; irc = irn; irn = ti;
  }
  // rc == r0 here (6 swaps). fcr region scratch now dead -> repack fc_w into it.
  k_fcr<<<dim3((FCRN + 255)/256), B, 0, stream>>>(fcw, fcr, dtf);
  // ---- decoder (fc1 fused; writes d_out directly) ----
  k_conve<<<dim3(EE/32), dim3(512), 0, stream>>>(xc, rc, ei, bn0g, bn0b,
                                                 convw, convb, bn1g, bn1b,
                                                 fcr, fcb, bn2g, bn2b,
                                                 fc1w, fc1b, d_out, dtf);
}

// Round 17
// 582.807 us; speedup vs baseline: 1.0849x; 1.0849x over previous
//
#include <hip/hip_runtime.h>
#include <hip/hip_bf16.h>

typedef __hip_bfloat16 bf16;
typedef __attribute__((ext_vector_type(8))) short short8_t;
typedef __attribute__((ext_vector_type(4))) unsigned short ushort4_t;
typedef __attribute__((ext_vector_type(4))) float float4_t;
typedef __attribute__((ext_vector_type(16))) float float16_t;

#define NN 5000
#define EE 8192
#define DM 200
#define NLAY 6
#define NFC 96
#define PPOS 196
#define FLATK 18816
#define NCLS 13
#define EPSC 1e-5f
// fcr coalesced layout: [dgrp(7)][pt(7)][g(6)][kch(64)][row(32)][8 bf16]
#define FCRN (7*7*6*64*32*8)   // 4,816,896 elements = 9.6 MB

__device__ __forceinline__ float b2f(bf16 v){ return __bfloat162float(v); }
__device__ __forceinline__ float us2f(unsigned short u){ return __uint_as_float(((unsigned int)u) << 16); }
__device__ __forceinline__ float ldf(const void* p, int i, int bf){
  return bf ? b2f(((const bf16*)p)[i]) : ((const float*)p)[i];
}
__device__ __forceinline__ unsigned short f2bu(float f){
  bf16 b = __float2bfloat16(f);
  unsigned short u;
  __builtin_memcpy(&u, &b, 2);
  return u;
}
__device__ __forceinline__ int clampN(int g){ return ((unsigned)g < (unsigned)NN) ? g : 0; }

// ---------------- dtype probe ----------------
__global__ void k_dtype(const void* __restrict__ bn1g, int* __restrict__ flag){
  if (blockIdx.x == 0 && threadIdx.x == 0)
    *flag = (*(const unsigned short*)bn1g == 0x3F80u) ? 1 : 0;
}

// ---------------- inputs -> working copies: x fp32, r/ir bf16 (quad-vectorized) ----
// region sizes NN*DM=1,000,000 and EE*DM=1,638,400 are both ≡0 mod 4 -> quads
// never straddle a region boundary. bf16 paths are bit-exact copies/shifts.
__global__ void k_cvt(const void* __restrict__ nfeat, const void* __restrict__ ef,
                      const void* __restrict__ ief, float* __restrict__ x0,
                      bf16* __restrict__ r0, bf16* __restrict__ ir0,
                      const int* __restrict__ dtf){
  const int bf = *dtf;
  const int totq = (NN*DM + 2*EE*DM) / 4;
  for (int q = blockIdx.x*blockDim.x + threadIdx.x; q < totq; q += gridDim.x*blockDim.x){
    int i = q*4;
    if (i < NN*DM){
      if (bf){
        ushort4_t v = *(const ushort4_t*)((const unsigned short*)nfeat + i);
        float4 o; o.x = us2f(v[0]); o.y = us2f(v[1]); o.z = us2f(v[2]); o.w = us2f(v[3]);
        *(float4*)(x0 + i) = o;
      } else {
        *(float4*)(x0 + i) = *(const float4*)((const float*)nfeat + i);
      }
    } else if (i < NN*DM + EE*DM){
      int j = i - NN*DM;
      if (bf){
        *(ushort4_t*)((unsigned short*)r0 + j) = *(const ushort4_t*)((const unsigned short*)ef + j);
      } else {
        float4 v = *(const float4*)((const float*)ef + j);
        ushort4_t o; o[0] = f2bu(v.x); o[1] = f2bu(v.y); o[2] = f2bu(v.z); o[3] = f2bu(v.w);
        *(ushort4_t*)((unsigned short*)r0 + j) = o;
      }
    } else {
      int j = i - NN*DM - EE*DM;
      if (bf){
        *(ushort4_t*)((unsigned short*)ir0 + j) = *(const ushort4_t*)((const unsigned short*)ief + j);
      } else {
        float4 v = *(const float4*)((const float*)ief + j);
        ushort4_t o; o[0] = f2bu(v.x); o[1] = f2bu(v.y); o[2] = f2bu(v.z); o[3] = f2bu(v.w);
        *(ushort4_t*)((unsigned short*)ir0 + j) = o;
      }
    }
  }
}

__global__ void k_zero(float* __restrict__ p, int n){
  int i = blockIdx.x*blockDim.x + threadIdx.x;
  if (i < n) p[i] = 0.f;
}

__global__ void k_deg(const int* __restrict__ ei0, const int* __restrict__ iei0,
                      float* __restrict__ degf, float* __restrict__ degi){
  int e = blockIdx.x*blockDim.x + threadIdx.x;
  if (e < EE){
    atomicAdd(&degf[clampN(ei0[e])], 1.f);
    atomicAdd(&degi[clampN(iei0[e])], 1.f);
  }
}

// dinv folded in: f(d) = d>0 ? rsqrt(d) : 0   (degrees are integers >= 0)
__global__ void k_norm(const int* __restrict__ ei, const int* __restrict__ iei,
                       const float* __restrict__ degf, const float* __restrict__ degi,
                       float* __restrict__ nfv, float* __restrict__ niv){
  int e = blockIdx.x*blockDim.x + threadIdx.x;
  if (e < EE){
    float ds0 = degf[clampN(ei[e])];
    float ds1 = degf[clampN(ei[EE + e])];
    float di0 = degi[clampN(iei[e])];
    float di1 = degi[clampN(iei[EE + e])];
    float f0 = ds0 > 0.f ? rsqrtf(ds0) : 0.f;
    float f1 = ds1 > 0.f ? rsqrtf(ds1) : 0.f;
    float g0 = di0 > 0.f ? rsqrtf(di0) : 0.f;
    float g1 = di1 > 0.f ? rsqrtf(di1) : 0.f;
    nfv[e] = f0 * f1;
    niv[e] = g0 * g1;
  }
}

// ---------------- fc_w repack, v8 coalesced layout ----------------
// fcr[dgrp][pt][g][kch][row][8]: a wave's 32 lanes at fixed kch read 32
// consecutive 16B chunks -> each FLOAD instruction reads one contiguous 1 KB block
// (was: 32 cache lines scattered across 1.4 MB). This was the -45% decoder win.
__global__ void k_fcr(const void* __restrict__ fc_w, bf16* __restrict__ outp,
                      const int* __restrict__ dtf){
  const int bf = *dtf;
  int i = blockIdx.x*blockDim.x + threadIdx.x;
  if (i >= FCRN) return;
  int j    = i & 7;
  int row  = (i >> 3) & 31;
  int kch  = (i >> 8) & 63;
  int rest = i >> 14;            // (dgrp*7 + pt)*6 + g
  int g = rest % 6;
  int rest2 = rest / 6;          // dgrp*7 + pt
  int pt = rest2 % 7;
  int dgrp = rest2 / 7;
  int d = dgrp*32 + row;
  int cl = kch >> 2, pidx = kch & 3;
  int p = pt*32 + pidx*8 + j;
  int c = g*16 + cl;
  float v = 0.f;
  if (p < PPOS && d < DM) v = ldf(fc_w, d*FLATK + c*PPOS + p, bf);
  outp[i] = __float2bfloat16(v);
}

// ---------------- weight transpose: wt[job][layer][n<224][k<208] bf16 ----------------
__global__ void k_wt(const void* __restrict__ Winp, const void* __restrict__ Woutp,
                     const void* __restrict__ Wloopp, const void* __restrict__ Wrelp,
                     bf16* __restrict__ wt, const int* __restrict__ dtf){
  const int bf = *dtf;
  const int per = 6*224*208;
  int i = blockIdx.x*blockDim.x + threadIdx.x;
  if (i >= 4*per) return;
  int job = i / per, rem = i - job*per;
  int layer = rem / (224*208), rem2 = rem - layer*(224*208);
  int n = rem2 / 208, k = rem2 - n*208;
  const void* src = (job==0) ? Wloopp : (job==1) ? Winp : (job==2) ? Woutp : Wrelp;
  float v = 0.f;
  if (n < DM && k < DM) v = ldf(src, (layer*DM + k)*DM + n, bf);
  wt[i] = __float2bfloat16(v);
}

// ---------------- GCN layer: both phases, ONE dispatch; vectorized staging -----
// 1181 blocks: 157 job0 (x@Wloop) + 256 job1 + 256 job2 + 256 job3 (r@Wrel) + 256 job4.
// job0 rows are block-exclusive -> its partial is stored NON-atomically into the
// xn buffer (dead data); k_tanh combines tanh((agg + xn)/3 + b) in place.
// Staging is quad-wide inline (v16 form — the v18 batched-MLP variant measured
// -7us/layer WORSE: gather latency is already TLP-hidden at 18 waves/CU).
// NOTE: plain __launch_bounds__ — any explicit occupancy attribute collapses the
// allocator to the 64-reg tier and spills (measured v4/v12/v14: 180 MB scratch).
__global__ __launch_bounds__(256) void k_gcn(
    const float* __restrict__ x,
    const bf16* __restrict__ rin, const bf16* __restrict__ irin,
    bf16* __restrict__ rout, bf16* __restrict__ irout,
    const int* __restrict__ ei, const int* __restrict__ iei,
    const float* __restrict__ nfv, const float* __restrict__ niv,
    const bf16* __restrict__ wt, int layer, float* __restrict__ agg,
    float* __restrict__ xw)
{
  __shared__ short Ah[32][216];
  __shared__ short Al[32][216];
  __shared__ int dst_s[32];
  const int tid = threadIdx.x;
  const int bid = blockIdx.x;
  int job, m0;
  if (bid < 157){ job = 0; m0 = bid*32; }
  else if (bid < 413){ job = 1; m0 = (bid-157)*32; }
  else if (bid < 669){ job = 2; m0 = (bid-413)*32; }
  else if (bid < 925){ job = 3; m0 = (bid-669)*32; }
  else { job = 4; m0 = (bid-925)*32; }
  const int wsel = (job <= 2) ? job : 3;
  const bf16* W = wt + (wsel*6 + layer)*224*208;
  const bool do_lo = (job <= 2);

  if (tid < 32){
    int row = m0 + tid;
    int d = 0;
    if (job == 1) d = clampN(ei[EE + row]);
    else if (job == 2) d = clampN(iei[EE + row]);
    dst_s[tid] = d;
  }
  // ---- vectorized staging: 32 rows x 52 quads (k = q*4) ----
  for (int t = tid; t < 32*52; t += 256){
    int m = t / 52, q = t - m*52;
    int k = q*4;
    int row = m0 + m;
    float a0 = 0.f, a1 = 0.f, a2 = 0.f, a3 = 0.f;
    if (q < 50){
      if (job == 0){
        if (row < NN){
          float4 v = *(const float4*)(x + row*DM + k);
          a0 = v.x; a1 = v.y; a2 = v.z; a3 = v.w;
        }
      } else if (job <= 2){
        const int* idx = (job == 1) ? ei : iei;
        const bf16* rr = (job == 1) ? rin : irin;
        const float nf = (job == 1) ? nfv[row] : niv[row];
        float4 v = *(const float4*)(x + clampN(idx[row])*DM + k);
        ushort4_t rv = *(const ushort4_t*)((const unsigned short*)rr + row*DM + k);
        a0 = (v.x - us2f(rv[0])) * nf;
        a1 = (v.y - us2f(rv[1])) * nf;
        a2 = (v.z - us2f(rv[2])) * nf;
        a3 = (v.w - us2f(rv[3])) * nf;
      } else {
        const bf16* rr = (job == 3) ? rin : irin;
        ushort4_t rv = *(const ushort4_t*)((const unsigned short*)rr + row*DM + k);
        a0 = us2f(rv[0]); a1 = us2f(rv[1]); a2 = us2f(rv[2]); a3 = us2f(rv[3]);
      }
    }
    unsigned short h0 = f2bu(a0), h1 = f2bu(a1), h2 = f2bu(a2), h3 = f2bu(a3);
    ushort4_t hv; hv[0] = h0; hv[1] = h1; hv[2] = h2; hv[3] = h3;
    *(ushort4_t*)&Ah[m][k] = hv;
    if (do_lo){
      ushort4_t lv;
      lv[0] = f2bu(a0 - us2f(h0));
      lv[1] = f2bu(a1 - us2f(h1));
      lv[2] = f2bu(a2 - us2f(h2));
      lv[3] = f2bu(a3 - us2f(h3));
      *(ushort4_t*)&Al[m][k] = lv;
    }
  }
  __syncthreads();

  const int lane = tid & 63, wave = tid >> 6;
  const int half = lane >> 5, ln = lane & 31;
  const bool has2 = (wave < 3);
  const bf16* Wn0 = W + (wave*32 + ln)*208;
  const bf16* Wn1 = W + ((wave+4)*32 + ln)*208;
  float16_t acc0 = {};
  float16_t acc1 = {};
  #pragma unroll
  for (int kk = 0; kk < 13; kk++){
    const int ko = kk*16 + half*8;
    short8_t ahf = *(const short8_t*)&Ah[ln][ko];
    short8_t b0 = *(const short8_t*)(Wn0 + ko);
    acc0 = __builtin_amdgcn_mfma_f32_32x32x16_bf16(ahf, b0, acc0, 0, 0, 0);
    short8_t alf = {};
    if (do_lo){
      alf = *(const short8_t*)&Al[ln][ko];
      acc0 = __builtin_amdgcn_mfma_f32_32x32x16_bf16(alf, b0, acc0, 0, 0, 0);
    }
    if (has2){
      short8_t b1 = *(const short8_t*)(Wn1 + ko);
      acc1 = __builtin_amdgcn_mfma_f32_32x32x16_bf16(ahf, b1, acc1, 0, 0, 0);
      if (do_lo)
        acc1 = __builtin_amdgcn_mfma_f32_32x32x16_bf16(alf, b1, acc1, 0, 0, 0);
    }
  }
  #pragma unroll
  for (int s = 0; s < 2; s++){
    if (s == 1 && !has2) break;
    int n = ((s ? wave+4 : wave)*32) + ln;
    if (n >= DM) continue;
    #pragma unroll
    for (int rr = 0; rr < 16; rr++){
      int m = (rr & 3) + 8*(rr >> 2) + 4*half;
      int row = m0 + m;
      float v = s ? acc1[rr] : acc0[rr];
      if (job == 0){ if (row < NN) xw[row*DM + n] = v; }        // exclusive rows: no atomic
      else if (job <= 2){ atomicAdd(&agg[dst_s[m]*DM + n], v); }
      else if (job == 3){ rout[row*DM + n] = __float2bfloat16(v); }
      else              { irout[row*DM + n] = __float2bfloat16(v); }
    }
  }
}

// tanh epilogue, float4: xw holds job0's partial; agg holds jobs 1/2 scatter sums.
__global__ void k_tanh(float* __restrict__ agg, const void* __restrict__ bgcn,
                       int l, float* __restrict__ xw, const int* __restrict__ dtf){
  const int bf = *dtf;
  int q = blockIdx.x*blockDim.x + threadIdx.x;
  if (q < NN*DM/4){
    int idx = q*4;
    int d = idx % DM;           // DM%4==0 -> d..d+3 within row
    float4 a = *(const float4*)(agg + idx);
    float4 xv = *(const float4*)(xw + idx);
    xv.x = tanhf((a.x + xv.x)*(1.f/3.f) + ldf(bgcn, l*DM + d, bf));
    xv.y = tanhf((a.y + xv.y)*(1.f/3.f) + ldf(bgcn, l*DM + d + 1, bf));
    xv.z = tanhf((a.z + xv.z)*(1.f/3.f) + ldf(bgcn, l*DM + d + 2, bf));
    xv.w = tanhf((a.w + xv.w)*(1.f/3.f) + ldf(bgcn, l*DM + d + 3, bf));
    *(float4*)(xw + idx) = xv;
    float4 z = {0.f, 0.f, 0.f, 0.f};
    *(float4*)(agg + idx) = z;
  }
}

// ---------------- fused ConvE decoder (champion: coalesced fcr + fc1 fused) ----------------
// Structure: 32 edges/block, 256 blocks. Per pt (7) x sub (2): transient A-frag conv
// (3 channel-groups into 3 P sections) -> barrier -> FC 12 batches of 8, double-buffered
// B-loads (each a contiguous 1 KB block), issue-early batch 0 under conv. Epilogue:
// bn2/relu h2 into LDS, fused fc1 -> d_out (no h2 HBM round-trip).
__global__ __launch_bounds__(512) void k_conve(
    const float* __restrict__ xf, const bf16* __restrict__ rf,
    const int* __restrict__ ei0,
    const void* __restrict__ bn0g, const void* __restrict__ bn0b,
    const void* __restrict__ conv_w, const void* __restrict__ conv_b,
    const void* __restrict__ bn1g, const void* __restrict__ bn1b,
    const bf16* __restrict__ fcr, const void* __restrict__ fc_b,
    const void* __restrict__ bn2g, const void* __restrict__ bn2b,
    const void* __restrict__ fc1w, const void* __restrict__ fc1b,
    void* __restrict__ outp, const int* __restrict__ dtf)
{
  const int bfm = *dtf;
  __shared__ __attribute__((aligned(16))) unsigned short img_s[32][400];  // 25.6 KB
  __shared__ __attribute__((aligned(16))) short P_s[3*32*520];            // 99.8 KB
  __shared__ __attribute__((aligned(16))) unsigned short cw_s[96*72];     // 13.8 KB
  __shared__ float bnp_s[3][96];                                          // 1.2 KB
  const int tid = threadIdx.x;
  const int e0 = blockIdx.x * 32;
  const int lane = tid & 63;
  const int wave = tid >> 6;
  const int half = lane >> 5;
  const int ln   = lane & 31;
  const int m16  = lane & 15;
  const int q4   = (lane >> 4) & 3;

  {
    const float s0 = ldf(bn0g, 0, bfm) * rsqrtf(1.f + EPSC);
    const float c0 = ldf(bn0b, 0, bfm);
    for (int t = tid; t < 32*400; t += 512){
      int me = t / 400, i = t - me*400;
      int e = e0 + me;
      int j = i >> 1;
      float v = (i & 1) ? b2f(rf[e*DM + j]) : xf[clampN(ei0[e])*DM + j];
      img_s[me][i] = f2bu(v * s0 + c0);
    }
    for (int t = tid; t < 96*72; t += 512){
      int c = t / 72, tau = t - c*72;
      float v = (tau < 49) ? ldf(conv_w, c*49 + tau, bfm) : 0.f;
      cw_s[t] = f2bu(v);
    }
    if (tid < 96){
      bnp_s[0][tid] = ldf(bn1g, tid, bfm) * rsqrtf(1.f + EPSC);
      bnp_s[1][tid] = ldf(bn1b, tid, bfm);
      bnp_s[2][tid] = ldf(conv_b, tid, bfm);
    }
  }

  int doff[2][8];
  #pragma unroll
  for (int kk = 0; kk < 2; kk++)
    #pragma unroll
    for (int j = 0; j < 8; j++){
      int tau = kk*32 + q4*8 + j;
      int kh = tau / 7, kw = tau - kh*7;
      doff[kk][j] = (tau < 49) ? kh*20 + kw : 0;
    }

  const int dA0 = wave*32 + ln;
  const bool fcact = (wave < 7);
  float16_t facc = {};

  __syncthreads();

#define FLOAD(BUF, BIDX) { \
    _Pragma("unroll") \
    for (int t_ = 0; t_ < 8; t_++){ \
      int it_ = (BIDX)*8 + t_; \
      int g_ = it_ >> 5; int itm_ = it_ & 31; int kch_ = itm_*2 + half; \
      BUF[t_] = *(const short8_t*)(frW + (g_*64 + kch_)*256 + ln*8); \
    } }
#define FCONS(BUF, BIDX) { \
    _Pragma("unroll") \
    for (int t_ = 0; t_ < 8; t_++){ \
      int it_ = (BIDX)*8 + t_; \
      int g_ = it_ >> 5; int itm_ = it_ & 31; int kch_ = itm_*2 + half; \
      int cl_ = kch_ >> 2, pidx_ = kch_ & 3; \
      short8_t af_ = *(const short8_t*)&P_s[g_*16640 + ln*520 + cl_*32 + ((pidx_ ^ (cl_ & 3))*8)]; \
      facc = __builtin_amdgcn_mfma_f32_32x32x16_bf16(af_, BUF[t_], facc, 0, 0, 0); \
    } }
#define PSTORE(CA, MS) { \
    _Pragma("unroll") \
    for (int r2_ = 0; r2_ < 2; r2_++){ \
      int ploc_ = (MS)*16 + q4*4 + r2_*2; \
      int pg_ = pt*32 + ploc_; \
      float v0_ = ((CA)[r2_*2]   + cbv) * s1v + bb1v;  v0_ = v0_ > 0.f ? v0_ : 0.f; \
      float v1_ = ((CA)[r2_*2+1] + cbv) * s1v + bb1v;  v1_ = v1_ > 0.f ? v1_ : 0.f; \
      if (pg_     >= PPOS) v0_ = 0.f; \
      if (pg_ + 1 >= PPOS) v1_ = 0.f; \
      unsigned int pk_ = (unsigned int)f2bu(v0_) | ((unsigned int)f2bu(v1_) << 16); \
      int sb_ = (ploc_ >> 3) ^ (m16 & 3); \
      *(unsigned int*)&P_s[g*16640 + eL*520 + m16*32 + sb_*8 + (ploc_ & 7)] = pk_; \
    } }

  #pragma unroll 1
  for (int pt = 0; pt < 7; pt++){
    int pbase0, pbase1;
    {
      int p0 = pt*32 + m16;
      int p1 = pt*32 + 16 + m16;
      int oh0 = p0 / 14, ow0 = p0 - oh0*14;
      int oh1 = p1 / 14, ow1 = p1 - oh1*14;
      pbase0 = (p0 < PPOS) ? oh0*20 + ow0 : 0;
      pbase1 = (p1 < PPOS) ? oh1*20 + ow1 : 0;
    }
    #pragma unroll 1
    for (int sub = 0; sub < 2; sub++){
      const bf16* frW = fcr + ((wave*7 + pt)*6 + sub*3)*16384;
      short8_t BbA[8], BbB[8];
      if (fcact) FLOAD(BbA, 0);

      #pragma unroll
      for (int e = 0; e < 4; e++){
        const int eL = wave*4 + e;
        const unsigned short* ib = &img_s[eL][0];
        short8_t A00, A01, A10, A11;
        #pragma unroll
        for (int j = 0; j < 8; j++){
          A00[j] = (short)ib[pbase0 + doff[0][j]];
          A01[j] = (short)ib[pbase0 + doff[1][j]];
          A10[j] = (short)ib[pbase1 + doff[0][j]];
          A11[j] = (short)ib[pbase1 + doff[1][j]];
        }
        #pragma unroll
        for (int g = 0; g < 3; g++){
          const int cidx = (sub*3 + g)*16 + m16;
          short8_t Bg0 = *(const short8_t*)&cw_s[cidx*72 + q4*8];
          short8_t Bg1 = *(const short8_t*)&cw_s[cidx*72 + 32 + q4*8];
          const float s1v  = bnp_s[0][cidx];
          const float bb1v = bnp_s[1][cidx];
          const float cbv  = bnp_s[2][cidx];
          float4_t ca0 = {0.f,0.f,0.f,0.f};
          ca0 = __builtin_amdgcn_mfma_f32_16x16x32_bf16(A00, Bg0, ca0, 0, 0, 0);
          ca0 = __builtin_amdgcn_mfma_f32_16x16x32_bf16(A01, Bg1, ca0, 0, 0, 0);
          PSTORE(ca0, 0);
          float4_t ca1 = {0.f,0.f,0.f,0.f};
          ca1 = __builtin_amdgcn_mfma_f32_16x16x32_bf16(A10, Bg0, ca1, 0, 0, 0);
          ca1 = __builtin_amdgcn_mfma_f32_16x16x32_bf16(A11, Bg1, ca1, 0, 0, 0);
          PSTORE(ca1, 1);
        }
      }
      __syncthreads();
      if (fcact){
        #pragma unroll 1
        for (int bb = 0; bb < 6; bb++){
          const int b0 = bb*2, b1 = bb*2 + 1;
          FLOAD(BbB, b1);
          FCONS(BbA, b0);
          if (bb < 5) FLOAD(BbA, b0 + 2);
          FCONS(BbB, b1);
        }
      }
      __syncthreads();
    }
  }

  // ---- epilogue 1: h2 = relu((facc + fc_b)*s2 + bn2b) -> LDS (P_s reused) ----
  float* h2s = (float*)P_s;    // 32 x 204 f32 (float4-aligned rows)
  if (fcact && dA0 < DM){
    const float s2  = ldf(bn2g, dA0, bfm) * rsqrtf(1.f + EPSC);
    const float bb2 = ldf(bn2b, dA0, bfm);
    const float fb  = ldf(fc_b, dA0, bfm);
    #pragma unroll
    for (int rr = 0; rr < 16; rr++){
      int m = (rr & 3) + 8*(rr >> 2) + 4*half;
      float v = (facc[rr] + fb) * s2 + bb2;
      h2s[m*204 + dA0] = v > 0.f ? v : 0.f;
    }
  }
  __syncthreads();
  // ---- epilogue 2: fused fc1 -> d_out (32 edges x 13 classes), float4 LDS reads ----
  if (tid < 32*NCLS){
    int e = tid / NCLS, n = tid - e*NCLS;
    const float4* h4p = (const float4*)(h2s + e*204);
    float s = ldf(fc1b, n, bfm);
    #pragma unroll 2
    for (int d4 = 0; d4 < 50; d4++){
      float4 h4 = h4p[d4];
      int d = d4*4;
      s += h4.x * ldf(fc1w, n*DM + d, bfm);
      s += h4.y * ldf(fc1w, n*DM + d + 1, bfm);
      s += h4.z * ldf(fc1w, n*DM + d + 2, bfm);
      s += h4.w * ldf(fc1w, n*DM + d + 3, bfm);
    }
    int idx = (e0 + e)*NCLS + n;
    if (bfm) ((bf16*)outp)[idx] = __float2bfloat16(s);
    else     ((float*)outp)[idx] = s;
  }
#undef FLOAD
#undef FCONS
#undef PSTORE
}

extern "C" void kernel_launch(void* const* d_in, const int* in_sizes, int n_in,
                              void* d_out, int out_size, void* d_ws, size_t ws_size,
                              hipStream_t stream){
  const void* nfeat = d_in[0];
  const void* ef    = d_in[1];
  const void* ief   = d_in[2];
  const void* Winp  = d_in[3];
  const void* Woutp = d_in[4];
  const void* Wloopp= d_in[5];
  const void* Wrelp = d_in[6];
  const void* bgcn  = d_in[7];
  const void* bn0g  = d_in[8];
  const void* bn0b  = d_in[9];
  const void* convw = d_in[10];
  const void* convb = d_in[11];
  const void* bn1g  = d_in[12];
  const void* bn1b  = d_in[13];
  const void* fcw   = d_in[14];
  const void* fcb   = d_in[15];
  const void* bn2g  = d_in[16];
  const void* bn2b  = d_in[17];
  const void* fc1w  = d_in[18];
  const void* fc1b  = d_in[19];
  const int* ei     = (const int*)d_in[20];   // [2][EE]
  const int* iei    = (const int*)d_in[21];

  // ---- workspace carve: ~30.5 MB ----
  char* base = (char*)d_ws;
  int*   dtf  = (int*)base;                      base += 16;
  float* x0   = (float*)base;                    base += NN*DM*4;
  float* x1   = (float*)base;                    base += NN*DM*4;
  float* agg  = (float*)base;                    base += NN*DM*4;
  float* degf = (float*)base;                    base += NN*4;
  float* degi = (float*)base;                    base += NN*4;
  float* nfv  = (float*)base;                    base += EE*4;
  float* niv  = (float*)base;                    base += EE*4;
  bf16*  r0   = (bf16*)base;                     base += EE*DM*2;
  bf16*  ir0  = (bf16*)base;                     base += EE*DM*2;
  bf16*  wt   = (bf16*)base;                     base += 4*6*224*208*2;
  bf16*  fcr  = (bf16*)base;                     base += FCRN*2;   // 9.6 MB
  // r/ir double-buffer scratch lives in the fcr region during the GCN loop
  // (fcr packed AFTER the loop; 6 layers = even #swaps -> final r/ir back in r0/ir0)
  bf16*  rB   = fcr;
  bf16*  irB  = fcr + EE*DM;

  const dim3 B(256);
  k_dtype<<<dim3(1), dim3(64), 0, stream>>>(bn1g, dtf);
  k_cvt<<<dim3(1024), B, 0, stream>>>(nfeat, ef, ief, x0, r0, ir0, dtf);
  k_zero<<<dim3((2*NN + 255)/256), B, 0, stream>>>(degf, 2*NN);
  k_zero<<<dim3((NN*DM + 255)/256), B, 0, stream>>>(agg, NN*DM);
  k_deg<<<dim3((EE + 255)/256), B, 0, stream>>>(ei, iei, degf, degi);
  k_norm<<<dim3((EE + 255)/256), B, 0, stream>>>(ei, iei, degf, degi, nfv, niv);
  k_wt<<<dim3((4*6*224*208 + 255)/256), B, 0, stream>>>(Winp, Woutp, Wloopp, Wrelp, wt, dtf);

  float* xc = x0; float* xn = x1;
  bf16* rc = r0;  bf16* irc = ir0;
  bf16* rn = rB;  bf16* irn = irB;
  for (int l = 0; l < NLAY; l++){
    k_gcn<<<dim3(1181), B, 0, stream>>>(xc, rc, irc, rn, irn, ei, iei, nfv, niv, wt, l, agg, xn);
    k_tanh<<<dim3((NN*DM/4 + 255)/256), B, 0, stream>>>(agg, bgcn, l, xn, dtf);
    float* t = xc; xc = xn; xn = t;
    bf16* tr = rc; rc = rn; rn = tr;
    bf16* ti = irc; irc = irn; irn = ti;
  }
  // rc == r0 here (6 swaps). fcr region scratch now dead -> repack fc_w into it.
  k_fcr<<<dim3((FCRN + 255)/256), B, 0, stream>>>(fcw, fcr, dtf);
  // ---- decoder (fc1 fused; writes d_out directly) ----
  k_conve<<<dim3(EE/32), dim3(512), 0, stream>>>(xc, rc, ei, bn0g, bn0b,
                                                 convw, convb, bn1g, bn1b,
                                                 fcr, fcb, bn2g, bn2b,
                                                 fc1w, fc1b, d_out, dtf);
}

// Round 18
// 581.842 us; speedup vs baseline: 1.0867x; 1.0017x over previous
//
#include <hip/hip_runtime.h>
#include <hip/hip_bf16.h>

typedef __hip_bfloat16 bf16;
typedef __attribute__((ext_vector_type(8))) short short8_t;
typedef __attribute__((ext_vector_type(4))) unsigned short ushort4_t;
typedef __attribute__((ext_vector_type(4))) float float4_t;
typedef __attribute__((ext_vector_type(16))) float float16_t;

#define NN 5000
#define EE 8192
#define DM 200
#define NLAY 6
#define NFC 96
#define PPOS 196
#define FLATK 18816
#define NCLS 13
#define EPSC 1e-5f
// fcr coalesced layout: [dgrp(7)][pt(7)][g(6)][kch(64)][row(32)][8 bf16]
#define FCRN (7*7*6*64*32*8)   // 4,816,896 elements = 9.6 MB
// fused setup work partition
#define CVTQ  ((NN*DM + 2*EE*DM)/4)     // 1,069,200 cvt quads
#define SETB1 (CVTQ + 2*NN)             // + deg zero (scalar)
#define SETB2 (SETB1 + NN*DM/4)         // + agg zero quads
#define SETTOT (SETB2 + 4*6*224*208)    // + wt elements

__device__ __forceinline__ float b2f(bf16 v){ return __bfloat162float(v); }
__device__ __forceinline__ float us2f(unsigned short u){ return __uint_as_float(((unsigned int)u) << 16); }
__device__ __forceinline__ float ldf(const void* p, int i, int bf){
  return bf ? b2f(((const bf16*)p)[i]) : ((const float*)p)[i];
}
__device__ __forceinline__ unsigned short f2bu(float f){
  bf16 b = __float2bfloat16(f);
  unsigned short u;
  __builtin_memcpy(&u, &b, 2);
  return u;
}
__device__ __forceinline__ int clampN(int g){ return ((unsigned)g < (unsigned)NN) ? g : 0; }

// ---------------- dtype probe ----------------
__global__ void k_dtype(const void* __restrict__ bn1g, int* __restrict__ flag){
  if (blockIdx.x == 0 && threadIdx.x == 0)
    *flag = (*(const unsigned short*)bn1g == 0x3F80u) ? 1 : 0;
}

// ---------------- fused setup: cvt + deg-zero + agg-zero + wt (independent regions) ----
// v20: was 4 serial launches (k_cvt, k_zero x2, k_wt); all writes are index-disjoint,
// so one grid-stride kernel removes 3 dispatch fill/drain boundaries.
// cvt: region sizes NN*DM / EE*DM are ≡0 mod 4 -> quads never straddle regions;
// bf16 paths are bit-exact copies/shifts. degf/degi contiguous -> one 2*NN zero span.
__global__ void k_setup(const void* __restrict__ nfeat, const void* __restrict__ ef,
                        const void* __restrict__ ief, float* __restrict__ x0,
                        bf16* __restrict__ r0, bf16* __restrict__ ir0,
                        float* __restrict__ degf, float* __restrict__ agg,
                        const void* __restrict__ Winp, const void* __restrict__ Woutp,
                        const void* __restrict__ Wloopp, const void* __restrict__ Wrelp,
                        bf16* __restrict__ wt, const int* __restrict__ dtf){
  const int bf = *dtf;
  for (int t = blockIdx.x*blockDim.x + threadIdx.x; t < SETTOT; t += gridDim.x*blockDim.x){
    if (t < CVTQ){
      int i = t*4;
      if (i < NN*DM){
        if (bf){
          ushort4_t v = *(const ushort4_t*)((const unsigned short*)nfeat + i);
          float4 o; o.x = us2f(v[0]); o.y = us2f(v[1]); o.z = us2f(v[2]); o.w = us2f(v[3]);
          *(float4*)(x0 + i) = o;
        } else {
          *(float4*)(x0 + i) = *(const float4*)((const float*)nfeat + i);
        }
      } else if (i < NN*DM + EE*DM){
        int j = i - NN*DM;
        if (bf){
          *(ushort4_t*)((unsigned short*)r0 + j) = *(const ushort4_t*)((const unsigned short*)ef + j);
        } else {
          float4 v = *(const float4*)((const float*)ef + j);
          ushort4_t o; o[0] = f2bu(v.x); o[1] = f2bu(v.y); o[2] = f2bu(v.z); o[3] = f2bu(v.w);
          *(ushort4_t*)((unsigned short*)r0 + j) = o;
        }
      } else {
        int j = i - NN*DM - EE*DM;
        if (bf){
          *(ushort4_t*)((unsigned short*)ir0 + j) = *(const ushort4_t*)((const unsigned short*)ief + j);
        } else {
          float4 v = *(const float4*)((const float*)ief + j);
          ushort4_t o; o[0] = f2bu(v.x); o[1] = f2bu(v.y); o[2] = f2bu(v.z); o[3] = f2bu(v.w);
          *(ushort4_t*)((unsigned short*)ir0 + j) = o;
        }
      }
    } else if (t < SETB1){
      degf[t - CVTQ] = 0.f;                  // covers degf then degi (contiguous)
    } else if (t < SETB2){
      float4 z = {0.f,0.f,0.f,0.f};
      *(float4*)(agg + (t - SETB1)*4) = z;
    } else {
      int i = t - SETB2;
      const int per = 6*224*208;
      int job = i / per, rem = i - job*per;
      int layer = rem / (224*208), rem2 = rem - layer*(224*208);
      int n = rem2 / 208, k = rem2 - n*208;
      const void* src = (job==0) ? Wloopp : (job==1) ? Winp : (job==2) ? Woutp : Wrelp;
      float v = 0.f;
      if (n < DM && k < DM) v = ldf(src, (layer*DM + k)*DM + n, bf);
      wt[i] = __float2bfloat16(v);
    }
  }
}

__global__ void k_deg(const int* __restrict__ ei0, const int* __restrict__ iei0,
                      float* __restrict__ degf, float* __restrict__ degi){
  int e = blockIdx.x*blockDim.x + threadIdx.x;
  if (e < EE){
    atomicAdd(&degf[clampN(ei0[e])], 1.f);
    atomicAdd(&degi[clampN(iei0[e])], 1.f);
  }
}

// dinv folded in: f(d) = d>0 ? rsqrt(d) : 0   (degrees are integers >= 0)
__global__ void k_norm(const int* __restrict__ ei, const int* __restrict__ iei,
                       const float* __restrict__ degf, const float* __restrict__ degi,
                       float* __restrict__ nfv, float* __restrict__ niv){
  int e = blockIdx.x*blockDim.x + threadIdx.x;
  if (e < EE){
    float ds0 = degf[clampN(ei[e])];
    float ds1 = degf[clampN(ei[EE + e])];
    float di0 = degi[clampN(iei[e])];
    float di1 = degi[clampN(iei[EE + e])];
    float f0 = ds0 > 0.f ? rsqrtf(ds0) : 0.f;
    float f1 = ds1 > 0.f ? rsqrtf(ds1) : 0.f;
    float g0 = di0 > 0.f ? rsqrtf(di0) : 0.f;
    float g1 = di1 > 0.f ? rsqrtf(di1) : 0.f;
    nfv[e] = f0 * f1;
    niv[e] = g0 * g1;
  }
}

// ---------------- fc_w repack, v8 coalesced layout ----------------
// fcr[dgrp][pt][g][kch][row][8]: a wave's 32 lanes at fixed kch read 32
// consecutive 16B chunks -> each FLOAD instruction reads one contiguous 1 KB block
// (was: 32 cache lines scattered across 1.4 MB). This was the -45% decoder win.
__global__ void k_fcr(const void* __restrict__ fc_w, bf16* __restrict__ outp,
                      const int* __restrict__ dtf){
  const int bf = *dtf;
  int i = blockIdx.x*blockDim.x + threadIdx.x;
  if (i >= FCRN) return;
  int j    = i & 7;
  int row  = (i >> 3) & 31;
  int kch  = (i >> 8) & 63;
  int rest = i >> 14;            // (dgrp*7 + pt)*6 + g
  int g = rest % 6;
  int rest2 = rest / 6;          // dgrp*7 + pt
  int pt = rest2 % 7;
  int dgrp = rest2 / 7;
  int d = dgrp*32 + row;
  int cl = kch >> 2, pidx = kch & 3;
  int p = pt*32 + pidx*8 + j;
  int c = g*16 + cl;
  float v = 0.f;
  if (p < PPOS && d < DM) v = ldf(fc_w, d*FLATK + c*PPOS + p, bf);
  outp[i] = __float2bfloat16(v);
}

// ---------------- GCN layer: both phases, ONE dispatch; vectorized staging -----
// 1181 blocks: 157 job0 (x@Wloop) + 256 job1 + 256 job2 + 256 job3 (r@Wrel) + 256 job4.
// job0 rows are block-exclusive -> its partial is stored NON-atomically into the
// xn buffer (dead data); k_tanh combines tanh((agg + xn)/3 + b) in place.
// Staging is quad-wide inline (the v18 batched-MLP variant measured WORSE:
// gather latency is already TLP-hidden at 18 waves/CU).
// NOTE: plain __launch_bounds__ — any explicit occupancy attribute collapses the
// allocator to the 64-reg tier and spills (measured v4/v12/v14: 180 MB scratch).
__global__ __launch_bounds__(256) void k_gcn(
    const float* __restrict__ x,
    const bf16* __restrict__ rin, const bf16* __restrict__ irin,
    bf16* __restrict__ rout, bf16* __restrict__ irout,
    const int* __restrict__ ei, const int* __restrict__ iei,
    const float* __restrict__ nfv, const float* __restrict__ niv,
    const bf16* __restrict__ wt, int layer, float* __restrict__ agg,
    float* __restrict__ xw)
{
  __shared__ short Ah[32][216];
  __shared__ short Al[32][216];
  __shared__ int dst_s[32];
  const int tid = threadIdx.x;
  const int bid = blockIdx.x;
  int job, m0;
  if (bid < 157){ job = 0; m0 = bid*32; }
  else if (bid < 413){ job = 1; m0 = (bid-157)*32; }
  else if (bid < 669){ job = 2; m0 = (bid-413)*32; }
  else if (bid < 925){ job = 3; m0 = (bid-669)*32; }
  else { job = 4; m0 = (bid-925)*32; }
  const int wsel = (job <= 2) ? job : 3;
  const bf16* W = wt + (wsel*6 + layer)*224*208;
  const bool do_lo = (job <= 2);

  if (tid < 32){
    int row = m0 + tid;
    int d = 0;
    if (job == 1) d = clampN(ei[EE + row]);
    else if (job == 2) d = clampN(iei[EE + row]);
    dst_s[tid] = d;
  }
  // ---- vectorized staging: 32 rows x 52 quads (k = q*4) ----
  for (int t = tid; t < 32*52; t += 256){
    int m = t / 52, q = t - m*52;
    int k = q*4;
    int row = m0 + m;
    float a0 = 0.f, a1 = 0.f, a2 = 0.f, a3 = 0.f;
    if (q < 50){
      if (job == 0){
        if (row < NN){
          float4 v = *(const float4*)(x + row*DM + k);
          a0 = v.x; a1 = v.y; a2 = v.z; a3 = v.w;
        }
      } else if (job <= 2){
        const int* idx = (job == 1) ? ei : iei;
        const bf16* rr = (job == 1) ? rin : irin;
        const float nf = (job == 1) ? nfv[row] : niv[row];
        float4 v = *(const float4*)(x + clampN(idx[row])*DM + k);
        ushort4_t rv = *(const ushort4_t*)((const unsigned short*)rr + row*DM + k);
        a0 = (v.x - us2f(rv[0])) * nf;
        a1 = (v.y - us2f(rv[1])) * nf;
        a2 = (v.z - us2f(rv[2])) * nf;
        a3 = (v.w - us2f(rv[3])) * nf;
      } else {
        const bf16* rr = (job == 3) ? rin : irin;
        ushort4_t rv = *(const ushort4_t*)((const unsigned short*)rr + row*DM + k);
        a0 = us2f(rv[0]); a1 = us2f(rv[1]); a2 = us2f(rv[2]); a3 = us2f(rv[3]);
      }
    }
    unsigned short h0 = f2bu(a0), h1 = f2bu(a1), h2 = f2bu(a2), h3 = f2bu(a3);
    ushort4_t hv; hv[0] = h0; hv[1] = h1; hv[2] = h2; hv[3] = h3;
    *(ushort4_t*)&Ah[m][k] = hv;
    if (do_lo){
      ushort4_t lv;
      lv[0] = f2bu(a0 - us2f(h0));
      lv[1] = f2bu(a1 - us2f(h1));
      lv[2] = f2bu(a2 - us2f(h2));
      lv[3] = f2bu(a3 - us2f(h3));
      *(ushort4_t*)&Al[m][k] = lv;
    }
  }
  __syncthreads();

  const int lane = tid & 63, wave = tid >> 6;
  const int half = lane >> 5, ln = lane & 31;
  const bool has2 = (wave < 3);
  const bf16* Wn0 = W + (wave*32 + ln)*208;
  const bf16* Wn1 = W + ((wave+4)*32 + ln)*208;
  float16_t acc0 = {};
  float16_t acc1 = {};
  #pragma unroll
  for (int kk = 0; kk < 13; kk++){
    const int ko = kk*16 + half*8;
    short8_t ahf = *(const short8_t*)&Ah[ln][ko];
    short8_t b0 = *(const short8_t*)(Wn0 + ko);
    acc0 = __builtin_amdgcn_mfma_f32_32x32x16_bf16(ahf, b0, acc0, 0, 0, 0);
    short8_t alf = {};
    if (do_lo){
      alf = *(const short8_t*)&Al[ln][ko];
      acc0 = __builtin_amdgcn_mfma_f32_32x32x16_bf16(alf, b0, acc0, 0, 0, 0);
    }
    if (has2){
      short8_t b1 = *(const short8_t*)(Wn1 + ko);
      acc1 = __builtin_amdgcn_mfma_f32_32x32x16_bf16(ahf, b1, acc1, 0, 0, 0);
      if (do_lo)
        acc1 = __builtin_amdgcn_mfma_f32_32x32x16_bf16(alf, b1, acc1, 0, 0, 0);
    }
  }
  #pragma unroll
  for (int s = 0; s < 2; s++){
    if (s == 1 && !has2) break;
    int n = ((s ? wave+4 : wave)*32) + ln;
    if (n >= DM) continue;
    #pragma unroll
    for (int rr = 0; rr < 16; rr++){
      int m = (rr & 3) + 8*(rr >> 2) + 4*half;
      int row = m0 + m;
      float v = s ? acc1[rr] : acc0[rr];
      if (job == 0){ if (row < NN) xw[row*DM + n] = v; }        // exclusive rows: no atomic
      else if (job <= 2){ atomicAdd(&agg[dst_s[m]*DM + n], v); }
      else if (job == 3){ rout[row*DM + n] = __float2bfloat16(v); }
      else              { irout[row*DM + n] = __float2bfloat16(v); }
    }
  }
}

// tanh epilogue, float4: xw holds job0's partial; agg holds jobs 1/2 scatter sums.
__global__ void k_tanh(float* __restrict__ agg, const void* __restrict__ bgcn,
                       int l, float* __restrict__ xw, const int* __restrict__ dtf){
  const int bf = *dtf;
  int q = blockIdx.x*blockDim.x + threadIdx.x;
  if (q < NN*DM/4){
    int idx = q*4;
    int d = idx % DM;           // DM%4==0 -> d..d+3 within row
    float4 a = *(const float4*)(agg + idx);
    float4 xv = *(const float4*)(xw + idx);
    xv.x = tanhf((a.x + xv.x)*(1.f/3.f) + ldf(bgcn, l*DM + d, bf));
    xv.y = tanhf((a.y + xv.y)*(1.f/3.f) + ldf(bgcn, l*DM + d + 1, bf));
    xv.z = tanhf((a.z + xv.z)*(1.f/3.f) + ldf(bgcn, l*DM + d + 2, bf));
    xv.w = tanhf((a.w + xv.w)*(1.f/3.f) + ldf(bgcn, l*DM + d + 3, bf));
    *(float4*)(xw + idx) = xv;
    float4 z = {0.f, 0.f, 0.f, 0.f};
    *(float4*)(agg + idx) = z;
  }
}

// ---------------- fused ConvE decoder (champion: coalesced fcr + fc1 fused) ----------------
// Structure: 32 edges/block, 256 blocks. Per pt (7) x sub (2): transient A-frag conv
// (3 channel-groups into 3 P sections) -> barrier -> FC 12 batches of 8, double-buffered
// B-loads (each a contiguous 1 KB block), issue-early batch 0 under conv. Epilogue:
// bn2/relu h2 into LDS, fused fc1 -> d_out (no h2 HBM round-trip).
__global__ __launch_bounds__(512) void k_conve(
    const float* __restrict__ xf, const bf16* __restrict__ rf,
    const int* __restrict__ ei0,
    const void* __restrict__ bn0g, const void* __restrict__ bn0b,
    const void* __restrict__ conv_w, const void* __restrict__ conv_b,
    const void* __restrict__ bn1g, const void* __restrict__ bn1b,
    const bf16* __restrict__ fcr, const void* __restrict__ fc_b,
    const void* __restrict__ bn2g, const void* __restrict__ bn2b,
    const void* __restrict__ fc1w, const void* __restrict__ fc1b,
    void* __restrict__ outp, const int* __restrict__ dtf)
{
  const int bfm = *dtf;
  __shared__ __attribute__((aligned(16))) unsigned short img_s[32][400];  // 25.6 KB
  __shared__ __attribute__((aligned(16))) short P_s[3*32*520];            // 99.8 KB
  __shared__ __attribute__((aligned(16))) unsigned short cw_s[96*72];     // 13.8 KB
  __shared__ float bnp_s[3][96];                                          // 1.2 KB
  const int tid = threadIdx.x;
  const int e0 = blockIdx.x * 32;
  const int lane = tid & 63;
  const int wave = tid >> 6;
  const int half = lane >> 5;
  const int ln   = lane & 31;
  const int m16  = lane & 15;
  const int q4   = (lane >> 4) & 3;

  {
    const float s0 = ldf(bn0g, 0, bfm) * rsqrtf(1.f + EPSC);
    const float c0 = ldf(bn0b, 0, bfm);
    for (int t = tid; t < 32*400; t += 512){
      int me = t / 400, i = t - me*400;
      int e = e0 + me;
      int j = i >> 1;
      float v = (i & 1) ? b2f(rf[e*DM + j]) : xf[clampN(ei0[e])*DM + j];
      img_s[me][i] = f2bu(v * s0 + c0);
    }
    for (int t = tid; t < 96*72; t += 512){
      int c = t / 72, tau = t - c*72;
      float v = (tau < 49) ? ldf(conv_w, c*49 + tau, bfm) : 0.f;
      cw_s[t] = f2bu(v);
    }
    if (tid < 96){
      bnp_s[0][tid] = ldf(bn1g, tid, bfm) * rsqrtf(1.f + EPSC);
      bnp_s[1][tid] = ldf(bn1b, tid, bfm);
      bnp_s[2][tid] = ldf(conv_b, tid, bfm);
    }
  }

  int doff[2][8];
  #pragma unroll
  for (int kk = 0; kk < 2; kk++)
    #pragma unroll
    for (int j = 0; j < 8; j++){
      int tau = kk*32 + q4*8 + j;
      int kh = tau / 7, kw = tau - kh*7;
      doff[kk][j] = (tau < 49) ? kh*20 + kw : 0;
    }

  const int dA0 = wave*32 + ln;
  const bool fcact = (wave < 7);
  float16_t facc = {};

  __syncthreads();

#define FLOAD(BUF, BIDX) { \
    _Pragma("unroll") \
    for (int t_ = 0; t_ < 8; t_++){ \
      int it_ = (BIDX)*8 + t_; \
      int g_ = it_ >> 5; int itm_ = it_ & 31; int kch_ = itm_*2 + half; \
      BUF[t_] = *(const short8_t*)(frW + (g_*64 + kch_)*256 + ln*8); \
    } }
#define FCONS(BUF, BIDX) { \
    _Pragma("unroll") \
    for (int t_ = 0; t_ < 8; t_++){ \
      int it_ = (BIDX)*8 + t_; \
      int g_ = it_ >> 5; int itm_ = it_ & 31; int kch_ = itm_*2 + half; \
      int cl_ = kch_ >> 2, pidx_ = kch_ & 3; \
      short8_t af_ = *(const short8_t*)&P_s[g_*16640 + ln*520 + cl_*32 + ((pidx_ ^ (cl_ & 3))*8)]; \
      facc = __builtin_amdgcn_mfma_f32_32x32x16_bf16(af_, BUF[t_], facc, 0, 0, 0); \
    } }
#define PSTORE(CA, MS) { \
    _Pragma("unroll") \
    for (int r2_ = 0; r2_ < 2; r2_++){ \
      int ploc_ = (MS)*16 + q4*4 + r2_*2; \
      int pg_ = pt*32 + ploc_; \
      float v0_ = ((CA)[r2_*2]   + cbv) * s1v + bb1v;  v0_ = v0_ > 0.f ? v0_ : 0.f; \
      float v1_ = ((CA)[r2_*2+1] + cbv) * s1v + bb1v;  v1_ = v1_ > 0.f ? v1_ : 0.f; \
      if (pg_     >= PPOS) v0_ = 0.f; \
      if (pg_ + 1 >= PPOS) v1_ = 0.f; \
      unsigned int pk_ = (unsigned int)f2bu(v0_) | ((unsigned int)f2bu(v1_) << 16); \
      int sb_ = (ploc_ >> 3) ^ (m16 & 3); \
      *(unsigned int*)&P_s[g*16640 + eL*520 + m16*32 + sb_*8 + (ploc_ & 7)] = pk_; \
    } }

  #pragma unroll 1
  for (int pt = 0; pt < 7; pt++){
    int pbase0, pbase1;
    {
      int p0 = pt*32 + m16;
      int p1 = pt*32 + 16 + m16;
      int oh0 = p0 / 14, ow0 = p0 - oh0*14;
      int oh1 = p1 / 14, ow1 = p1 - oh1*14;
      pbase0 = (p0 < PPOS) ? oh0*20 + ow0 : 0;
      pbase1 = (p1 < PPOS) ? oh1*20 + ow1 : 0;
    }
    #pragma unroll 1
    for (int sub = 0; sub < 2; sub++){
      const bf16* frW = fcr + ((wave*7 + pt)*6 + sub*3)*16384;
      short8_t BbA[8], BbB[8];
      if (fcact) FLOAD(BbA, 0);

      #pragma unroll
      for (int e = 0; e < 4; e++){
        const int eL = wave*4 + e;
        const unsigned short* ib = &img_s[eL][0];
        short8_t A00, A01, A10, A11;
        #pragma unroll
        for (int j = 0; j < 8; j++){
          A00[j] = (short)ib[pbase0 + doff[0][j]];
          A01[j] = (short)ib[pbase0 + doff[1][j]];
          A10[j] = (short)ib[pbase1 + doff[0][j]];
          A11[j] = (short)ib[pbase1 + doff[1][j]];
        }
        #pragma unroll
        for (int g = 0; g < 3; g++){
          const int cidx = (sub*3 + g)*16 + m16;
          short8_t Bg0 = *(const short8_t*)&cw_s[cidx*72 + q4*8];
          short8_t Bg1 = *(const short8_t*)&cw_s[cidx*72 + 32 + q4*8];
          const float s1v  = bnp_s[0][cidx];
          const float bb1v = bnp_s[1][cidx];
          const float cbv  = bnp_s[2][cidx];
          float4_t ca0 = {0.f,0.f,0.f,0.f};
          ca0 = __builtin_amdgcn_mfma_f32_16x16x32_bf16(A00, Bg0, ca0, 0, 0, 0);
          ca0 = __builtin_amdgcn_mfma_f32_16x16x32_bf16(A01, Bg1, ca0, 0, 0, 0);
          PSTORE(ca0, 0);
          float4_t ca1 = {0.f,0.f,0.f,0.f};
          ca1 = __builtin_amdgcn_mfma_f32_16x16x32_bf16(A10, Bg0, ca1, 0, 0, 0);
          ca1 = __builtin_amdgcn_mfma_f32_16x16x32_bf16(A11, Bg1, ca1, 0, 0, 0);
          PSTORE(ca1, 1);
        }
      }
      __syncthreads();
      if (fcact){
        #pragma unroll 1
        for (int bb = 0; bb < 6; bb++){
          const int b0 = bb*2, b1 = bb*2 + 1;
          FLOAD(BbB, b1);
          FCONS(BbA, b0);
          if (bb < 5) FLOAD(BbA, b0 + 2);
          FCONS(BbB, b1);
        }
      }
      __syncthreads();
    }
  }

  // ---- epilogue 1: h2 = relu((facc + fc_b)*s2 + bn2b) -> LDS (P_s reused) ----
  float* h2s = (float*)P_s;    // 32 x 204 f32 (float4-aligned rows)
  if (fcact && dA0 < DM){
    const float s2  = ldf(bn2g, dA0, bfm) * rsqrtf(1.f + EPSC);
    const float bb2 = ldf(bn2b, dA0, bfm);
    const float fb  = ldf(fc_b, dA0, bfm);
    #pragma unroll
    for (int rr = 0; rr < 16; rr++){
      int m = (rr & 3) + 8*(rr >> 2) + 4*half;
      float v = (facc[rr] + fb) * s2 + bb2;
      h2s[m*204 + dA0] = v > 0.f ? v : 0.f;
    }
  }
  __syncthreads();
  // ---- epilogue 2: fused fc1 -> d_out (32 edges x 13 classes), float4 LDS reads ----
  if (tid < 32*NCLS){
    int e = tid / NCLS, n = tid - e*NCLS;
    const float4* h4p = (const float4*)(h2s + e*204);
    float s = ldf(fc1b, n, bfm);
    #pragma unroll 2
    for (int d4 = 0; d4 < 50; d4++){
      float4 h4 = h4p[d4];
      int d = d4*4;
      s += h4.x * ldf(fc1w, n*DM + d, bfm);
      s += h4.y * ldf(fc1w, n*DM + d + 1, bfm);
      s += h4.z * ldf(fc1w, n*DM + d + 2, bfm);
      s += h4.w * ldf(fc1w, n*DM + d + 3, bfm);
    }
    int idx = (e0 + e)*NCLS + n;
    if (bfm) ((bf16*)outp)[idx] = __float2bfloat16(s);
    else     ((float*)outp)[idx] = s;
  }
#undef FLOAD
#undef FCONS
#undef PSTORE
}

extern "C" void kernel_launch(void* const* d_in, const int* in_sizes, int n_in,
                              void* d_out, int out_size, void* d_ws, size_t ws_size,
                              hipStream_t stream){
  const void* nfeat = d_in[0];
  const void* ef    = d_in[1];
  const void* ief   = d_in[2];
  const void* Winp  = d_in[3];
  const void* Woutp = d_in[4];
  const void* Wloopp= d_in[5];
  const void* Wrelp = d_in[6];
  const void* bgcn  = d_in[7];
  const void* bn0g  = d_in[8];
  const void* bn0b  = d_in[9];
  const void* convw = d_in[10];
  const void* convb = d_in[11];
  const void* bn1g  = d_in[12];
  const void* bn1b  = d_in[13];
  const void* fcw   = d_in[14];
  const void* fcb   = d_in[15];
  const void* bn2g  = d_in[16];
  const void* bn2b  = d_in[17];
  const void* fc1w  = d_in[18];
  const void* fc1b  = d_in[19];
  const int* ei     = (const int*)d_in[20];   // [2][EE]
  const int* iei    = (const int*)d_in[21];

  // ---- workspace carve: ~30.5 MB ----
  char* base = (char*)d_ws;
  int*   dtf  = (int*)base;                      base += 16;
  float* x0   = (float*)base;                    base += NN*DM*4;
  float* x1   = (float*)base;                    base += NN*DM*4;
  float* agg  = (float*)base;                    base += NN*DM*4;
  float* degf = (float*)base;                    base += NN*4;
  float* degi = (float*)base;                    base += NN*4;
  float* nfv  = (float*)base;                    base += EE*4;
  float* niv  = (float*)base;                    base += EE*4;
  bf16*  r0   = (bf16*)base;                     base += EE*DM*2;
  bf16*  ir0  = (bf16*)base;                     base += EE*DM*2;
  bf16*  wt   = (bf16*)base;                     base += 4*6*224*208*2;
  bf16*  fcr  = (bf16*)base;                     base += FCRN*2;   // 9.6 MB
  // r/ir double-buffer scratch lives in the fcr region during the GCN loop
  // (fcr packed AFTER the loop; 6 layers = even #swaps -> final r/ir back in r0/ir0)
  bf16*  rB   = fcr;
  bf16*  irB  = fcr + EE*DM;

  const dim3 B(256);
  k_dtype<<<dim3(1), dim3(64), 0, stream>>>(bn1g, dtf);
  k_setup<<<dim3(2048), B, 0, stream>>>(nfeat, ef, ief, x0, r0, ir0, degf, agg,
                                        Winp, Woutp, Wloopp, Wrelp, wt, dtf);
  k_deg<<<dim3((EE + 255)/256), B, 0, stream>>>(ei, iei, degf, degi);
  k_norm<<<dim3((EE + 255)/256), B, 0, stream>>>(ei, iei, degf, degi, nfv, niv);

  float* xc = x0; float* xn = x1;
  bf16* rc = r0;  bf16* irc = ir0;
  bf16* rn = rB;  bf16* irn = irB;
  for (int l = 0; l < NLAY; l++){
    k_gcn<<<dim3(1181), B, 0, stream>>>(xc, rc, irc, rn, irn, ei, iei, nfv, niv, wt, l, agg, xn);
    k_tanh<<<dim3((NN*DM/4 + 255)/256), B, 0, stream>>>(agg, bgcn, l, xn, dtf);
    float* t = xc; xc = xn; xn = t;
    bf16* tr = rc; rc = rn; rn = tr;
    bf16* ti = irc; irc = irn; irn = ti;
  }
  // rc == r0 here (6 swaps). fcr region scratch now dead -> repack fc_w into it.
  k_fcr<<<dim3((FCRN + 255)/256), B, 0, stream>>>(fcw, fcr, dtf);
  // ---- decoder (fc1 fused; writes d_out directly) ----
  k_conve<<<dim3(EE/32), dim3(512), 0, stream>>>(xc, rc, ei, bn0g, bn0b,
                                                 convw, convb, bn1g, bn1b,
                                                 fcr, fcb, bn2g, bn2b,
                                                 fc1w, fc1b, d_out, dtf);
}